// Round 2
// baseline (700.794 us; speedup 1.0000x reference)
//
#include <hip/hip_runtime.h>
#include <hip/hip_bf16.h>

// Problem constants
#define M_VIEWS 6
#define N_ROWS  2048
#define D_IN    1152
#define D_HID   128
#define D_K     64
#define TOT_ROWS (M_VIEWS * N_ROWS)   // 12288
#define INVTAU   2.0f                 // 1/TAU

typedef short bf16x8 __attribute__((ext_vector_type(8)));
typedef float f32x4  __attribute__((ext_vector_type(4)));

// ---------------------------------------------------------------------------
// Kernel 1: x = x_all @ W + b   (fp32)
// ---------------------------------------------------------------------------
__global__ __launch_bounds__(256) void xgemm_kernel(
    const float* __restrict__ xall,  // [12288][1152]
    const float* __restrict__ W,     // [1152][128]
    const float* __restrict__ bias,  // [128]
    float* __restrict__ x)           // [12288][128]
{
    __shared__ float xl[8 * D_IN];
    const int row0 = blockIdx.x * 8;

    const float4* src = reinterpret_cast<const float4*>(xall + (size_t)row0 * D_IN);
    float4* dst = reinterpret_cast<float4*>(xl);
    for (int i = threadIdx.x; i < 8 * D_IN / 4; i += 256)
        dst[i] = src[i];
    __syncthreads();

    const int j = threadIdx.x & 127;
    const int g = threadIdx.x >> 7;   // 0 or 1

    float acc[4] = {0.f, 0.f, 0.f, 0.f};
    for (int d = 0; d < D_IN; ++d) {
        float w = W[d * D_HID + j];
        #pragma unroll
        for (int r = 0; r < 4; ++r)
            acc[r] += xl[(g * 4 + r) * D_IN + d] * w;
    }
    float bj = bias[j];
    #pragma unroll
    for (int r = 0; r < 4; ++r)
        x[(size_t)(row0 + g * 4 + r) * D_HID + j] = acc[r] + bj;
}

// ---------------------------------------------------------------------------
// Kernel 2: retrieve — E[mat][row] = P @ softmax(x[row] @ P), cast to bf16.
// ---------------------------------------------------------------------------
__global__ __launch_bounds__(256) void retrieve_kernel(
    const float* __restrict__ x,     // [12288][128]
    const float* __restrict__ U,     // [128][64]
    const float* __restrict__ V,     // [128][64]
    __hip_bfloat16* __restrict__ E)  // [2][12288][128]
{
    const int w    = threadIdx.x >> 6;
    const int lane = threadIdx.x & 63;
    const int row  = blockIdx.x * 4 + w;

    __shared__ float xs[4][D_HID];
    __shared__ float attns[4][D_K];

    float2 xv = reinterpret_cast<const float2*>(x + (size_t)row * D_HID)[lane];
    xs[w][2 * lane]     = xv.x;
    xs[w][2 * lane + 1] = xv.y;
    __syncthreads();

    #pragma unroll
    for (int mat = 0; mat < 2; ++mat) {
        const float* P = mat ? V : U;

        float lg = 0.f;
        for (int d = 0; d < D_HID; ++d)
            lg += xs[w][d] * P[d * D_K + lane];

        float mx = lg;
        #pragma unroll
        for (int s = 1; s < 64; s <<= 1) mx = fmaxf(mx, __shfl_xor(mx, s));
        float e = __expf(lg - mx);
        float sm = e;
        #pragma unroll
        for (int s = 1; s < 64; s <<= 1) sm += __shfl_xor(sm, s);
        float attn = e / sm;
        attns[w][lane] = attn;
        __syncthreads();

        float o0 = 0.f, o1 = 0.f;
        const int d0 = 2 * lane;
        for (int kk = 0; kk < D_K; ++kk) {
            float a = attns[w][kk];
            o0 += a * P[d0 * D_K + kk];
            o1 += a * P[(d0 + 1) * D_K + kk];
        }
        __hip_bfloat16* Er = E + ((size_t)mat * TOT_ROWS + row) * D_HID;
        Er[d0]     = __float2bfloat16(o0);
        Er[d0 + 1] = __float2bfloat16(o1);
        __syncthreads();
    }
}

// ---------------------------------------------------------------------------
// Kernel 3: pair LSE with PER-LANE online logsumexp (no per-tile shuffles).
// Block = (job, q-tile of 64 rows). 4 waves x 16 rows.
// Lane owns columns {lr, lr+16, lr+32, lr+48} of each 64-col strip; keeps
// running (max, sum) per row; cross-lane merge happens once at the end.
// Diagonal exclusion only occurs in the single tile pt == qt.
// ---------------------------------------------------------------------------
__global__ __launch_bounds__(256) void pair_lse_kernel(
    const __hip_bfloat16* __restrict__ E,  // [2][6][2048][128]
    float* __restrict__ out, float scale)
{
    const int blk = blockIdx.x;      // 60 jobs * 32 qtiles
    const int qt  = blk & 31;
    const int job = blk >> 5;        // 0..59
    const int mat = job / 30;
    const int pr  = job % 30;
    const int m   = pr / 5;
    int k = pr % 5; k += (k >= m);

    const __hip_bfloat16* Qm = E + ((size_t)mat * M_VIEWS + m) * N_ROWS * D_HID;
    const __hip_bfloat16* Kk = E + ((size_t)mat * M_VIEWS + k) * N_ROWS * D_HID;

    const int tid  = threadIdx.x;
    const int wave = tid >> 6;
    const int lane = tid & 63;
    const int lr   = lane & 15;   // frag row/col index
    const int lg   = lane >> 4;   // 0..3

    const int qrow0 = qt * 64 + wave * 16;

    // hoist A fragments (wave's 16 q-rows, 4 k-steps)
    bf16x8 afrag[4];
    const __hip_bfloat16* qrowp = Qm + (size_t)(qrow0 + lr) * D_HID;
    #pragma unroll
    for (int s = 0; s < 4; ++s)
        afrag[s] = *reinterpret_cast<const bf16x8*>(qrowp + s * 32 + lg * 8);

    // per-lane running state, 4 rows per lane (row = lg*4 + j), scaled domain
    float mrun[4], lrun[4], pos[4];
    #pragma unroll
    for (int j = 0; j < 4; ++j) { mrun[j] = -1e30f; lrun[j] = 0.f; pos[j] = 0.f; }

    #pragma unroll 2
    for (int pt = 0; pt < 32; ++pt) {
        // S strip: 16 rows x 64 cols = 4 col-tiles of 16x16
        f32x4 acc[4];
        #pragma unroll
        for (int ct = 0; ct < 4; ++ct) {
            f32x4 a = {0.f, 0.f, 0.f, 0.f};
            const __hip_bfloat16* krowp = Kk + (size_t)(pt * 64 + ct * 16 + lr) * D_HID;
            #pragma unroll
            for (int s = 0; s < 4; ++s) {
                bf16x8 bfrag = *reinterpret_cast<const bf16x8*>(krowp + s * 32 + lg * 8);
                a = __builtin_amdgcn_mfma_f32_16x16x32_bf16(afrag[s], bfrag, a, 0, 0, 0);
            }
            acc[ct] = a;
        }

        if (pt == qt) {
            // diagonal tile: exclude the self-sim element (one lane per row)
            #pragma unroll
            for (int j = 0; j < 4; ++j) {
                const bool dlane = (lr == lg * 4 + j);
                float v[4];
                #pragma unroll
                for (int ct = 0; ct < 4; ++ct) {
                    float w = acc[ct][j] * INVTAU;
                    bool excl = (ct == wave) && dlane;   // ct is compile-time
                    if (excl) pos[j] = w;
                    v[ct] = excl ? -INFINITY : w;
                }
                float tmax = fmaxf(fmaxf(v[0], v[1]), fmaxf(v[2], v[3]));
                float nm = fmaxf(mrun[j], tmax);
                float psum = __expf(v[0] - nm) + __expf(v[1] - nm)
                           + __expf(v[2] - nm) + __expf(v[3] - nm);
                lrun[j] = lrun[j] * __expf(mrun[j] - nm) + psum;
                mrun[j] = nm;
            }
        } else {
            // clean tile: branch-free per-lane update
            #pragma unroll
            for (int j = 0; j < 4; ++j) {
                float v0 = acc[0][j] * INVTAU;
                float v1 = acc[1][j] * INVTAU;
                float v2 = acc[2][j] * INVTAU;
                float v3 = acc[3][j] * INVTAU;
                float tmax = fmaxf(fmaxf(v0, v1), fmaxf(v2, v3));
                float nm = fmaxf(mrun[j], tmax);
                float psum = __expf(v0 - nm) + __expf(v1 - nm)
                           + __expf(v2 - nm) + __expf(v3 - nm);
                lrun[j] = lrun[j] * __expf(mrun[j] - nm) + psum;
                mrun[j] = nm;
            }
        }
    }

    // final cross-lane merge (once): combine (m,l) across the 16 lr lanes
    float contrib = 0.f;
    #pragma unroll
    for (int j = 0; j < 4; ++j) {
        float M = mrun[j], L = lrun[j];
        #pragma unroll
        for (int s = 1; s < 16; s <<= 1) {
            float Mo = __shfl_xor(M, s);
            float Lo = __shfl_xor(L, s);
            float nm = fmaxf(M, Mo);
            L = L * __expf(M - nm) + Lo * __expf(Mo - nm);
            M = nm;
        }
        float P = pos[j];
        #pragma unroll
        for (int s = 1; s < 16; s <<= 1) P += __shfl_xor(P, s);
        float lse = M + __logf(L);
        if (lr == 0) contrib += lse - P;
    }
    #pragma unroll
    for (int s = 1; s < 64; s <<= 1) contrib += __shfl_xor(contrib, s);

    __shared__ float bsum[4];
    if (lane == 0) bsum[wave] = contrib;
    __syncthreads();
    if (tid == 0)
        atomicAdd(out, (bsum[0] + bsum[1] + bsum[2] + bsum[3]) * scale);
}

// ---------------------------------------------------------------------------
extern "C" void kernel_launch(void* const* d_in, const int* in_sizes, int n_in,
                              void* d_out, int out_size, void* d_ws, size_t ws_size,
                              hipStream_t stream) {
    const float* xall = (const float*)d_in[0];
    const float* W    = (const float*)d_in[1];
    const float* b    = (const float*)d_in[2];
    const float* U    = (const float*)d_in[3];
    const float* V    = (const float*)d_in[4];
    float* out = (float*)d_out;

    float* x = (float*)d_ws;                                      // 6.29 MB
    __hip_bfloat16* E = (__hip_bfloat16*)((char*)d_ws + (size_t)TOT_ROWS * D_HID * 4);

    hipMemsetAsync(d_out, 0, sizeof(float), stream);

    xgemm_kernel<<<TOT_ROWS / 8, 256, 0, stream>>>(xall, W, b, x);
    retrieve_kernel<<<TOT_ROWS / 4, 256, 0, stream>>>(x, U, V, E);

    const float scale = 1.0f / ((float)N_ROWS * 60.0f);
    pair_lse_kernel<<<60 * 32, 256, 0, stream>>>(E, out, scale);
}

// Round 3
// 286.892 us; speedup vs baseline: 2.4427x; 2.4427x over previous
//
#include <hip/hip_runtime.h>
#include <hip/hip_bf16.h>

// Problem constants
#define M_VIEWS 6
#define N_ROWS  2048
#define D_IN    1152
#define D_HID   128
#define D_K     64
#define TOT_ROWS (M_VIEWS * N_ROWS)   // 12288
// E is pre-scaled by sqrt((1/tau) * log2(e)) = sqrt(2 * 1.44269504) so that
// E'.E' = (s/tau)*log2(e)  -> softmax-LSE runs in exp2/log2 domain, no muls.
#define SCALE_E 1.6986436f

typedef short bf16x8 __attribute__((ext_vector_type(8)));
typedef float f32x4  __attribute__((ext_vector_type(4)));

typedef __attribute__((address_space(1))) const void gvoid_t;
typedef __attribute__((address_space(3))) void svoid_t;

__device__ inline void async16(const void* g, void* l) {
    __builtin_amdgcn_global_load_lds((gvoid_t*)g, (svoid_t*)l, 16, 0, 0);
}

#if __has_builtin(__builtin_amdgcn_exp2f)
__device__ inline float fexp2(float x) { return __builtin_amdgcn_exp2f(x); }
#else
__device__ inline float fexp2(float x) { return exp2f(x); }
#endif
#if __has_builtin(__builtin_amdgcn_logf)
__device__ inline float flog2(float x) { return __builtin_amdgcn_logf(x); }
#else
__device__ inline float flog2(float x) { return log2f(x); }
#endif

// ---------------------------------------------------------------------------
// Kernel 0: split W into hi/lo bf16 in MFMA-fragment-friendly layout.
// frag (s=K-step of 32, ct=col-tile of 16): lane (lg=lane>>4, lr=lane&15)
// holds W[s*32+lg*8+i][ct*16+lr], i=0..7, stored contiguously per lane.
// ---------------------------------------------------------------------------
__global__ __launch_bounds__(64) void prep_w_kernel(
    const float* __restrict__ W,
    __hip_bfloat16* __restrict__ Whi, __hip_bfloat16* __restrict__ Wlo)
{
    const int s    = blockIdx.x >> 3;   // 0..35
    const int ct   = blockIdx.x & 7;    // 0..7
    const int lane = threadIdx.x;
    const int lg = lane >> 4, lr = lane & 15;
    bf16x8 hi, lo;
    #pragma unroll
    for (int i = 0; i < 8; ++i) {
        float w = W[(size_t)(s * 32 + lg * 8 + i) * D_HID + ct * 16 + lr];
        __hip_bfloat16 h = __float2bfloat16(w);
        float rem = w - __bfloat162float(h);
        __hip_bfloat16 l = __float2bfloat16(rem);
        hi[i] = *reinterpret_cast<const short*>(&h);
        lo[i] = *reinterpret_cast<const short*>(&l);
    }
    size_t off = ((size_t)(s * 8 + ct) * 64 + lane) * 8;
    *reinterpret_cast<bf16x8*>(Whi + off) = hi;
    *reinterpret_cast<bf16x8*>(Wlo + off) = lo;
}

// ---------------------------------------------------------------------------
// Kernel 1: x = x_all @ W + b via split-bf16 MFMA (3 terms: hh + lh + hl).
// Block = 64 rows, 4 waves x 16 rows. K = 1152 in 36 steps of 32.
// ---------------------------------------------------------------------------
__global__ __launch_bounds__(256) void xgemm_kernel(
    const float* __restrict__ xall,
    const __hip_bfloat16* __restrict__ Whi,
    const __hip_bfloat16* __restrict__ Wlo,
    const float* __restrict__ bias,
    float* __restrict__ x)
{
    const int wave = threadIdx.x >> 6, lane = threadIdx.x & 63;
    const int lg = lane >> 4, lr = lane & 15;
    const int arow = blockIdx.x * 64 + wave * 16 + lr;
    const float* ap = xall + (size_t)arow * D_IN;

    f32x4 acc[8];
    #pragma unroll
    for (int ct = 0; ct < 8; ++ct) acc[ct] = {0.f, 0.f, 0.f, 0.f};

    const bf16x8* whb = reinterpret_cast<const bf16x8*>(Whi) + lane;
    const bf16x8* wlb = reinterpret_cast<const bf16x8*>(Wlo) + lane;

    for (int s = 0; s < 36; ++s) {
        // A fragment: 8 consecutive f32, split into hi/lo bf16
        const float* a8 = ap + s * 32 + lg * 8;
        float4 va = *reinterpret_cast<const float4*>(a8);
        float4 vb = *reinterpret_cast<const float4*>(a8 + 4);
        float v[8] = {va.x, va.y, va.z, va.w, vb.x, vb.y, vb.z, vb.w};
        bf16x8 ah, al;
        #pragma unroll
        for (int i = 0; i < 8; ++i) {
            __hip_bfloat16 h = __float2bfloat16(v[i]);
            float rem = v[i] - __bfloat162float(h);
            __hip_bfloat16 l = __float2bfloat16(rem);
            ah[i] = *reinterpret_cast<const short*>(&h);
            al[i] = *reinterpret_cast<const short*>(&l);
        }
        #pragma unroll
        for (int ct = 0; ct < 8; ++ct) {
            bf16x8 wh = whb[(size_t)s * 512 + ct * 64];
            bf16x8 wl = wlb[(size_t)s * 512 + ct * 64];
            acc[ct] = __builtin_amdgcn_mfma_f32_16x16x32_bf16(ah, wh, acc[ct], 0, 0, 0);
            acc[ct] = __builtin_amdgcn_mfma_f32_16x16x32_bf16(al, wh, acc[ct], 0, 0, 0);
            acc[ct] = __builtin_amdgcn_mfma_f32_16x16x32_bf16(ah, wl, acc[ct], 0, 0, 0);
        }
    }

    const int orow0 = blockIdx.x * 64 + wave * 16 + lg * 4;
    #pragma unroll
    for (int ct = 0; ct < 8; ++ct) {
        float bj = bias[ct * 16 + lr];
        #pragma unroll
        for (int j = 0; j < 4; ++j)
            x[(size_t)(orow0 + j) * D_HID + ct * 16 + lr] = acc[ct][j] + bj;
    }
}

// ---------------------------------------------------------------------------
// Kernel 2: retrieve — E[mat][row] = SCALE_E * (P @ softmax(x[row] @ P)), bf16.
// ---------------------------------------------------------------------------
__global__ __launch_bounds__(256) void retrieve_kernel(
    const float* __restrict__ x,
    const float* __restrict__ U,
    const float* __restrict__ V,
    __hip_bfloat16* __restrict__ E)
{
    const int w    = threadIdx.x >> 6;
    const int lane = threadIdx.x & 63;
    const int row  = blockIdx.x * 4 + w;

    __shared__ float xs[4][D_HID];
    __shared__ float attns[4][D_K];

    float2 xv = reinterpret_cast<const float2*>(x + (size_t)row * D_HID)[lane];
    xs[w][2 * lane]     = xv.x;
    xs[w][2 * lane + 1] = xv.y;
    __syncthreads();

    #pragma unroll
    for (int mat = 0; mat < 2; ++mat) {
        const float* P = mat ? V : U;

        float lg = 0.f;
        for (int d = 0; d < D_HID; ++d)
            lg += xs[w][d] * P[d * D_K + lane];

        float mx = lg;
        #pragma unroll
        for (int s = 1; s < 64; s <<= 1) mx = fmaxf(mx, __shfl_xor(mx, s));
        float e = __expf(lg - mx);
        float sm = e;
        #pragma unroll
        for (int s = 1; s < 64; s <<= 1) sm += __shfl_xor(sm, s);
        float attn = e / sm;
        attns[w][lane] = attn;
        __syncthreads();

        float o0 = 0.f, o1 = 0.f;
        const int d0 = 2 * lane;
        for (int kk = 0; kk < D_K; ++kk) {
            float a = attns[w][kk];
            o0 += a * P[d0 * D_K + kk];
            o1 += a * P[(d0 + 1) * D_K + kk];
        }
        __hip_bfloat16* Er = E + ((size_t)mat * TOT_ROWS + row) * D_HID;
        Er[d0]     = __float2bfloat16(o0 * SCALE_E);
        Er[d0 + 1] = __float2bfloat16(o1 * SCALE_E);
        __syncthreads();
    }
}

// ---------------------------------------------------------------------------
// Kernel 3: pair LSE. Block = (job, q-tile of 128 rows), 4 waves x 32 rows.
// K-tiles (64x128 bf16 = 16 KB) double-buffered in LDS via global_load_lds
// (linear dest + inverse-swizzled source; swizzled ds_read). Per-lane online
// LSE in exp2 domain (scales folded into E). XCD-swizzled blockIdx.
// ---------------------------------------------------------------------------
__global__ __launch_bounds__(256) void pair_lse_kernel(
    const __hip_bfloat16* __restrict__ E,  // [2][6][2048][128], pre-scaled
    float* __restrict__ out, float scale)
{
    __shared__ __align__(16) unsigned char kbuf[2 * 16384];
    __shared__ float bsum[4];

    // XCD-aware bijective swizzle: 960 = 8 XCD x 120; all 16 q-tiles of a
    // job land on the same XCD so its K-panel stays L2-resident.
    const int bid    = blockIdx.x;
    const int linear = (bid & 7) * 120 + (bid >> 3);
    const int qt  = linear & 15;
    const int job = linear >> 4;         // 0..59
    const int mat = job / 30;
    const int pr  = job % 30;
    const int m   = pr / 5;
    int k = pr % 5; k += (k >= m);

    const __hip_bfloat16* Qm = E + ((size_t)(mat * M_VIEWS + m)) * N_ROWS * D_HID;
    const __hip_bfloat16* Kk = E + ((size_t)(mat * M_VIEWS + k)) * N_ROWS * D_HID;

    const int tid  = threadIdx.x;
    const int wave = tid >> 6, lane = tid & 63;
    const int lr = lane & 15, lg = lane >> 4;

    const int qrow0 = qt * 128 + wave * 32;

    // hoist A fragments: 2 row-frags x 4 k-steps
    bf16x8 afrag[2][4];
    #pragma unroll
    for (int rf = 0; rf < 2; ++rf) {
        const __hip_bfloat16* qp = Qm + (size_t)(qrow0 + rf * 16 + lr) * D_HID;
        #pragma unroll
        for (int s = 0; s < 4; ++s)
            afrag[rf][s] = *reinterpret_cast<const bf16x8*>(qp + s * 32 + lg * 8);
    }

    float mrun[2][4], lrun[2][4], pos[2][4];
    #pragma unroll
    for (int rf = 0; rf < 2; ++rf)
        #pragma unroll
        for (int j = 0; j < 4; ++j) {
            mrun[rf][j] = -1e30f; lrun[rf][j] = 0.f; pos[rf][j] = 0.f;
        }

    const int ptdiag = qt * 2 + (wave >> 1);
    const int ctd0   = (wave & 1) * 2;

    // prologue: stage tile 0 (linear LDS dest, inverse-swizzled source)
    {
        const char* src = (const char*)Kk;
        #pragma unroll
        for (int r = 0; r < 4; ++r) {
            int d  = r * 4096 + tid * 16;
            int so = d ^ (((d >> 8) & 7) << 4);
            async16(src + so, kbuf + (r * 4096 + wave * 1024));
        }
    }
    __syncthreads();

    int buf = 0;
    for (int pt = 0; pt < 32; ++pt) {
        if (pt < 31) {   // prefetch next tile into the other buffer
            const char* src = (const char*)Kk + (size_t)(pt + 1) * 16384;
            const int dbase = (buf ^ 1) * 16384;
            #pragma unroll
            for (int r = 0; r < 4; ++r) {
                int d  = r * 4096 + tid * 16;
                int so = d ^ (((d >> 8) & 7) << 4);
                async16(src + so, kbuf + dbase + (r * 4096 + wave * 1024));
            }
        }

        const unsigned char* kb = kbuf + buf * 16384;
        f32x4 acc[2][4];
        #pragma unroll
        for (int rf = 0; rf < 2; ++rf)
            #pragma unroll
            for (int ct = 0; ct < 4; ++ct) acc[rf][ct] = {0.f, 0.f, 0.f, 0.f};

        #pragma unroll
        for (int ct = 0; ct < 4; ++ct) {
            #pragma unroll
            for (int s = 0; s < 4; ++s) {
                int addr = ((ct * 16 + lr) * 256 + s * 64 + lg * 16) ^ ((lr & 7) << 4);
                bf16x8 bf = *reinterpret_cast<const bf16x8*>(kb + addr);
                acc[0][ct] = __builtin_amdgcn_mfma_f32_16x16x32_bf16(afrag[0][s], bf, acc[0][ct], 0, 0, 0);
                acc[1][ct] = __builtin_amdgcn_mfma_f32_16x16x32_bf16(afrag[1][s], bf, acc[1][ct], 0, 0, 0);
            }
        }

        const bool dtile = (pt == ptdiag);
        #pragma unroll
        for (int rf = 0; rf < 2; ++rf) {
            #pragma unroll
            for (int j = 0; j < 4; ++j) {
                float v0 = acc[rf][0][j], v1 = acc[rf][1][j];
                float v2 = acc[rf][2][j], v3 = acc[rf][3][j];
                if (dtile) {
                    const int cd = ctd0 + rf;     // wave-uniform
                    const bool dl = (lr == lg * 4 + j);
                    float dv = (cd == 0) ? v0 : (cd == 1) ? v1 : (cd == 2) ? v2 : v3;
                    if (dl) {
                        pos[rf][j] = dv;
                        if      (cd == 0) v0 = -INFINITY;
                        else if (cd == 1) v1 = -INFINITY;
                        else if (cd == 2) v2 = -INFINITY;
                        else              v3 = -INFINITY;
                    }
                }
                float tmax = fmaxf(fmaxf(v0, v1), fmaxf(v2, v3));
                float nm = fmaxf(mrun[rf][j], tmax);
                float ps = fexp2(v0 - nm) + fexp2(v1 - nm)
                         + fexp2(v2 - nm) + fexp2(v3 - nm);
                lrun[rf][j] = lrun[rf][j] * fexp2(mrun[rf][j] - nm) + ps;
                mrun[rf][j] = nm;
            }
        }
        __syncthreads();   // drains staging vmcnt; next buffer ready
        buf ^= 1;
    }

    // final cross-lane merge over the 16 lr-lanes, once
    float contrib = 0.f;
    #pragma unroll
    for (int rf = 0; rf < 2; ++rf) {
        #pragma unroll
        for (int j = 0; j < 4; ++j) {
            float Mv = mrun[rf][j], Lv = lrun[rf][j];
            #pragma unroll
            for (int s = 1; s < 16; s <<= 1) {
                float Mo = __shfl_xor(Mv, s);
                float Lo = __shfl_xor(Lv, s);
                float nm = fmaxf(Mv, Mo);
                Lv = Lv * fexp2(Mv - nm) + Lo * fexp2(Mo - nm);
                Mv = nm;
            }
            float P = pos[rf][j];
            #pragma unroll
            for (int s = 1; s < 16; s <<= 1) P += __shfl_xor(P, s);
            if (lr == 0) contrib += (Mv + flog2(Lv)) - P;   // log2 domain
        }
    }
    #pragma unroll
    for (int s = 1; s < 64; s <<= 1) contrib += __shfl_xor(contrib, s);

    if (lane == 0) bsum[wave] = contrib;
    __syncthreads();
    if (tid == 0)
        atomicAdd(out, (bsum[0] + bsum[1] + bsum[2] + bsum[3]) * scale);
}

// ---------------------------------------------------------------------------
extern "C" void kernel_launch(void* const* d_in, const int* in_sizes, int n_in,
                              void* d_out, int out_size, void* d_ws, size_t ws_size,
                              hipStream_t stream) {
    const float* xall = (const float*)d_in[0];
    const float* W    = (const float*)d_in[1];
    const float* b    = (const float*)d_in[2];
    const float* U    = (const float*)d_in[3];
    const float* V    = (const float*)d_in[4];
    float* out = (float*)d_out;

    float* x = (float*)d_ws;                                   // 6.29 MB
    __hip_bfloat16* E = (__hip_bfloat16*)((char*)d_ws + (size_t)TOT_ROWS * D_HID * 4);
    // W hi/lo fragments live in the E region (E is written later by retrieve)
    __hip_bfloat16* Whi = E;
    __hip_bfloat16* Wlo = E + 36 * 8 * 64 * 8;                 // +147456 elems

    hipMemsetAsync(d_out, 0, sizeof(float), stream);

    prep_w_kernel<<<36 * 8, 64, 0, stream>>>(W, Whi, Wlo);
    xgemm_kernel<<<TOT_ROWS / 64, 256, 0, stream>>>(xall, Whi, Wlo, b, x);
    retrieve_kernel<<<TOT_ROWS / 4, 256, 0, stream>>>(x, U, V, E);

    // scale = ln2 (log2->ln) / (N rows * 60 pair-jobs)
    const float scale = 0.6931471805599453f / (2048.0f * 60.0f);
    pair_lse_kernel<<<960, 256, 0, stream>>>(E, out, scale);
}

// Round 4
// 241.958 us; speedup vs baseline: 2.8963x; 1.1857x over previous
//
#include <hip/hip_runtime.h>
#include <hip/hip_bf16.h>

// Problem constants
#define M_VIEWS 6
#define N_ROWS  2048
#define D_IN    1152
#define D_HID   128
#define D_K     64
#define TOT_ROWS (M_VIEWS * N_ROWS)   // 12288
// E is pre-scaled by sqrt((1/tau) * log2(e)) so E'.E' = (s/tau)*log2(e):
// softmax-LSE runs in exp2/log2 domain with no per-element muls.
#define SCALE_E 1.6986436f

typedef short bf16x8 __attribute__((ext_vector_type(8)));
typedef float f32x4  __attribute__((ext_vector_type(4)));

typedef __attribute__((address_space(1))) const void gvoid_t;
typedef __attribute__((address_space(3))) void svoid_t;

__device__ inline void async16(const void* g, void* l) {
    __builtin_amdgcn_global_load_lds((gvoid_t*)g, (svoid_t*)l, 16, 0, 0);
}

#if __has_builtin(__builtin_amdgcn_exp2f)
__device__ inline float fexp2(float x) { return __builtin_amdgcn_exp2f(x); }
#else
__device__ inline float fexp2(float x) { return exp2f(x); }
#endif
#if __has_builtin(__builtin_amdgcn_logf)
__device__ inline float flog2(float x) { return __builtin_amdgcn_logf(x); }
#else
__device__ inline float flog2(float x) { return log2f(x); }
#endif

// ---------------------------------------------------------------------------
// Kernel 0: split W into hi/lo bf16 in MFMA-fragment layout.
// ---------------------------------------------------------------------------
__global__ __launch_bounds__(64) void prep_w_kernel(
    const float* __restrict__ W,
    __hip_bfloat16* __restrict__ Whi, __hip_bfloat16* __restrict__ Wlo)
{
    const int s    = blockIdx.x >> 3;   // 0..35
    const int ct   = blockIdx.x & 7;    // 0..7
    const int lane = threadIdx.x;
    const int lg = lane >> 4, lr = lane & 15;
    bf16x8 hi, lo;
    #pragma unroll
    for (int i = 0; i < 8; ++i) {
        float w = W[(size_t)(s * 32 + lg * 8 + i) * D_HID + ct * 16 + lr];
        __hip_bfloat16 h = __float2bfloat16(w);
        float rem = w - __bfloat162float(h);
        __hip_bfloat16 l = __float2bfloat16(rem);
        hi[i] = *reinterpret_cast<const short*>(&h);
        lo[i] = *reinterpret_cast<const short*>(&l);
    }
    size_t off = ((size_t)(s * 8 + ct) * 64 + lane) * 8;
    *reinterpret_cast<bf16x8*>(Whi + off) = hi;
    *reinterpret_cast<bf16x8*>(Wlo + off) = lo;
}

// ---------------------------------------------------------------------------
// Kernel 1: x = x_all @ W + b via split-bf16 MFMA, K-split over 4 waves.
// Block = 16 rows, 4 waves; wave w covers k in [w*288, w*288+288).
// Partial accumulators reduced through LDS by wave 0.
// ---------------------------------------------------------------------------
__global__ __launch_bounds__(256) void xgemm_kernel(
    const float* __restrict__ xall,
    const __hip_bfloat16* __restrict__ Whi,
    const __hip_bfloat16* __restrict__ Wlo,
    const float* __restrict__ bias,
    float* __restrict__ x)
{
    __shared__ f32x4 red[3 * 512];   // 24 KB
    const int wave = threadIdx.x >> 6, lane = threadIdx.x & 63;
    const int lg = lane >> 4, lr = lane & 15;
    const int row0 = blockIdx.x * 16;
    const float* ap = xall + (size_t)(row0 + lr) * D_IN + wave * 288;

    f32x4 acc[8];
    #pragma unroll
    for (int ct = 0; ct < 8; ++ct) acc[ct] = {0.f, 0.f, 0.f, 0.f};

    const bf16x8* whb = reinterpret_cast<const bf16x8*>(Whi) + lane;
    const bf16x8* wlb = reinterpret_cast<const bf16x8*>(Wlo) + lane;

    for (int s = 0; s < 9; ++s) {
        const int gs = wave * 9 + s;
        const float* a8 = ap + s * 32 + lg * 8;
        float4 va = *reinterpret_cast<const float4*>(a8);
        float4 vb = *reinterpret_cast<const float4*>(a8 + 4);
        float v[8] = {va.x, va.y, va.z, va.w, vb.x, vb.y, vb.z, vb.w};
        bf16x8 ah, al;
        #pragma unroll
        for (int i = 0; i < 8; ++i) {
            __hip_bfloat16 h = __float2bfloat16(v[i]);
            float rem = v[i] - __bfloat162float(h);
            __hip_bfloat16 l = __float2bfloat16(rem);
            ah[i] = *reinterpret_cast<const short*>(&h);
            al[i] = *reinterpret_cast<const short*>(&l);
        }
        #pragma unroll
        for (int ct = 0; ct < 8; ++ct) {
            bf16x8 wh = whb[(size_t)(gs * 8 + ct) * 64];
            bf16x8 wl = wlb[(size_t)(gs * 8 + ct) * 64];
            acc[ct] = __builtin_amdgcn_mfma_f32_16x16x32_bf16(ah, wh, acc[ct], 0, 0, 0);
            acc[ct] = __builtin_amdgcn_mfma_f32_16x16x32_bf16(al, wh, acc[ct], 0, 0, 0);
            acc[ct] = __builtin_amdgcn_mfma_f32_16x16x32_bf16(ah, wl, acc[ct], 0, 0, 0);
        }
    }

    if (wave > 0) {
        #pragma unroll
        for (int ct = 0; ct < 8; ++ct)
            red[(wave - 1) * 512 + ct * 64 + lane] = acc[ct];
    }
    __syncthreads();
    if (wave == 0) {
        const int orow0 = row0 + lg * 4;
        #pragma unroll
        for (int ct = 0; ct < 8; ++ct) {
            f32x4 a = acc[ct];
            a += red[ct * 64 + lane];
            a += red[512 + ct * 64 + lane];
            a += red[1024 + ct * 64 + lane];
            float bj = bias[ct * 16 + lr];
            #pragma unroll
            for (int j = 0; j < 4; ++j)
                x[(size_t)(orow0 + j) * D_HID + ct * 16 + lr] = a[j] + bj;
        }
    }
}

// ---------------------------------------------------------------------------
// Kernel 2: retrieve — E[mat][row] = SCALE_E * (P @ softmax(x[row] @ P)), bf16.
// ---------------------------------------------------------------------------
__global__ __launch_bounds__(256) void retrieve_kernel(
    const float* __restrict__ x,
    const float* __restrict__ U,
    const float* __restrict__ V,
    __hip_bfloat16* __restrict__ E)
{
    const int w    = threadIdx.x >> 6;
    const int lane = threadIdx.x & 63;
    const int row  = blockIdx.x * 4 + w;

    __shared__ float xs[4][D_HID];
    __shared__ float attns[4][D_K];

    float2 xv = reinterpret_cast<const float2*>(x + (size_t)row * D_HID)[lane];
    xs[w][2 * lane]     = xv.x;
    xs[w][2 * lane + 1] = xv.y;
    __syncthreads();

    #pragma unroll
    for (int mat = 0; mat < 2; ++mat) {
        const float* P = mat ? V : U;

        float lg = 0.f;
        for (int d = 0; d < D_HID; ++d)
            lg += xs[w][d] * P[d * D_K + lane];

        float mx = lg;
        #pragma unroll
        for (int s = 1; s < 64; s <<= 1) mx = fmaxf(mx, __shfl_xor(mx, s));
        float e = __expf(lg - mx);
        float sm = e;
        #pragma unroll
        for (int s = 1; s < 64; s <<= 1) sm += __shfl_xor(sm, s);
        float attn = e / sm;
        attns[w][lane] = attn;
        __syncthreads();

        float o0 = 0.f, o1 = 0.f;
        const int d0 = 2 * lane;
        for (int kk = 0; kk < D_K; ++kk) {
            float a = attns[w][kk];
            o0 += a * P[d0 * D_K + kk];
            o1 += a * P[(d0 + 1) * D_K + kk];
        }
        __hip_bfloat16* Er = E + ((size_t)mat * TOT_ROWS + row) * D_HID;
        Er[d0]     = __float2bfloat16(o0 * SCALE_E);
        Er[d0 + 1] = __float2bfloat16(o1 * SCALE_E);
        __syncthreads();
    }
}

// ---------------------------------------------------------------------------
// Kernel 3: pair LSE. Block = (job, q-tile of 256 rows), 8 waves x 32 rows.
// K-tile (64x128 bf16 = 16 KB) staged in FRAGMENT-ORDERED LDS layout:
// fragment f=(ct*4+s) occupies kbuf[f*1024 + lane*16] — global_load_lds with
// per-lane pre-swizzled source gives linear, conflict-free LDS reads with
// immediate offsets. Double-buffered. Per-lane online LSE in exp2 domain.
// ---------------------------------------------------------------------------
__global__ __launch_bounds__(512) void pair_lse_kernel(
    const __hip_bfloat16* __restrict__ E,  // [2][6][2048][128], pre-scaled
    float* __restrict__ out, float scale)
{
    __shared__ __align__(16) unsigned char kbuf[2 * 16384];
    __shared__ float bsum[8];

    // XCD-aware bijective swizzle: 480 = 8 XCD x 60; q-tiles of a job land
    // (mostly) on the same XCD so its K-panel stays L2-resident.
    const int bid    = blockIdx.x;
    const int linear = (bid & 7) * 60 + (bid >> 3);
    const int qt  = linear & 7;          // 0..7
    const int job = linear >> 3;         // 0..59
    const int mat = job / 30;
    const int pr  = job % 30;
    const int m   = pr / 5;
    int k = pr % 5; k += (k >= m);

    const __hip_bfloat16* Qm = E + ((size_t)(mat * M_VIEWS + m)) * N_ROWS * D_HID;
    const __hip_bfloat16* Kk = E + ((size_t)(mat * M_VIEWS + k)) * N_ROWS * D_HID;

    const int tid  = threadIdx.x;
    const int wave = tid >> 6, lane = tid & 63;
    const int lr = lane & 15, lg = lane >> 4;

    const int qrow0 = qt * 256 + wave * 32;

    // hoist A fragments: 2 row-frags x 4 k-steps (global reads, once)
    bf16x8 afrag[2][4];
    #pragma unroll
    for (int rf = 0; rf < 2; ++rf) {
        const __hip_bfloat16* qp = Qm + (size_t)(qrow0 + rf * 16 + lr) * D_HID;
        #pragma unroll
        for (int s = 0; s < 4; ++s)
            afrag[rf][s] = *reinterpret_cast<const bf16x8*>(qp + s * 32 + lg * 8);
    }

    float mrun[2][4], lrun[2][4], pos[2][4];
    #pragma unroll
    for (int rf = 0; rf < 2; ++rf)
        #pragma unroll
        for (int j = 0; j < 4; ++j) {
            mrun[rf][j] = -1e30f; lrun[rf][j] = 0.f; pos[rf][j] = 0.f;
        }

    const int ptdiag = qt * 4 + (wave >> 1);
    const int ctd0   = (wave & 1) * 2;

    // stage both fragments this wave owns for tile pt into buffer b.
    // LDS layout: frag f=(ct*4+s) at f*1024 + lane*16 holds
    // K[pt*64 + ct*16 + lr][s*32 + lg*8 .. +8]  (the exact MFMA B-fragment).
    #define STAGE(pt, b)                                                        \
        {                                                                       \
            const char* base = (const char*)Kk + (size_t)(pt) * 16384;          \
            _Pragma("unroll")                                                   \
            for (int i = 0; i < 2; ++i) {                                       \
                int f = wave * 2 + i;                                           \
                int ct_ = f >> 2, s_ = f & 3;                                   \
                async16(base + (ct_ * 16 + lr) * 256 + s_ * 64 + lg * 16,       \
                        kbuf + (b) * 16384 + f * 1024);                         \
            }                                                                   \
        }

    STAGE(0, 0);
    __syncthreads();

    const unsigned char* kb0 = kbuf + lane * 16;
    int buf = 0;
    for (int pt = 0; pt < 32; ++pt) {
        if (pt < 31) STAGE(pt + 1, buf ^ 1);

        const unsigned char* kb = kb0 + buf * 16384;
        f32x4 acc[2][4];
        #pragma unroll
        for (int rf = 0; rf < 2; ++rf)
            #pragma unroll
            for (int ct = 0; ct < 4; ++ct) acc[rf][ct] = {0.f, 0.f, 0.f, 0.f};

        #pragma unroll
        for (int ct = 0; ct < 4; ++ct) {
            #pragma unroll
            for (int s = 0; s < 4; ++s) {
                bf16x8 bf = *reinterpret_cast<const bf16x8*>(kb + (ct * 4 + s) * 1024);
                acc[0][ct] = __builtin_amdgcn_mfma_f32_16x16x32_bf16(afrag[0][s], bf, acc[0][ct], 0, 0, 0);
                acc[1][ct] = __builtin_amdgcn_mfma_f32_16x16x32_bf16(afrag[1][s], bf, acc[1][ct], 0, 0, 0);
            }
        }

        const bool dtile = (pt == ptdiag);
        #pragma unroll
        for (int rf = 0; rf < 2; ++rf) {
            #pragma unroll
            for (int j = 0; j < 4; ++j) {
                float v0 = acc[rf][0][j], v1 = acc[rf][1][j];
                float v2 = acc[rf][2][j], v3 = acc[rf][3][j];
                if (dtile) {
                    const int cd = ctd0 + rf;     // wave-uniform
                    const bool dl = (lr == lg * 4 + j);
                    float dv = (cd == 0) ? v0 : (cd == 1) ? v1 : (cd == 2) ? v2 : v3;
                    if (dl) {
                        pos[rf][j] = dv;
                        if      (cd == 0) v0 = -INFINITY;
                        else if (cd == 1) v1 = -INFINITY;
                        else if (cd == 2) v2 = -INFINITY;
                        else              v3 = -INFINITY;
                    }
                }
                float tmax = fmaxf(fmaxf(v0, v1), fmaxf(v2, v3));
                float nm = fmaxf(mrun[rf][j], tmax);
                float ps = fexp2(v0 - nm) + fexp2(v1 - nm)
                         + fexp2(v2 - nm) + fexp2(v3 - nm);
                lrun[rf][j] = lrun[rf][j] * fexp2(mrun[rf][j] - nm) + ps;
                mrun[rf][j] = nm;
            }
        }
        __syncthreads();   // drains staging vmcnt; next buffer ready
        buf ^= 1;
    }

    // final cross-lane merge over the 16 lr-lanes, once
    float contrib = 0.f;
    #pragma unroll
    for (int rf = 0; rf < 2; ++rf) {
        #pragma unroll
        for (int j = 0; j < 4; ++j) {
            float Mv = mrun[rf][j], Lv = lrun[rf][j];
            #pragma unroll
            for (int s = 1; s < 16; s <<= 1) {
                float Mo = __shfl_xor(Mv, s);
                float Lo = __shfl_xor(Lv, s);
                float nm = fmaxf(Mv, Mo);
                Lv = Lv * fexp2(Mv - nm) + Lo * fexp2(Mo - nm);
                Mv = nm;
            }
            float P = pos[rf][j];
            #pragma unroll
            for (int s = 1; s < 16; s <<= 1) P += __shfl_xor(P, s);
            if (lr == 0) contrib += (Mv + flog2(Lv)) - P;   // log2 domain
        }
    }
    #pragma unroll
    for (int s = 1; s < 64; s <<= 1) contrib += __shfl_xor(contrib, s);

    if (lane == 0) bsum[wave] = contrib;
    __syncthreads();
    if (tid == 0) {
        float t = 0.f;
        #pragma unroll
        for (int w = 0; w < 8; ++w) t += bsum[w];
        atomicAdd(out, t * scale);
    }
}

// ---------------------------------------------------------------------------
extern "C" void kernel_launch(void* const* d_in, const int* in_sizes, int n_in,
                              void* d_out, int out_size, void* d_ws, size_t ws_size,
                              hipStream_t stream) {
    const float* xall = (const float*)d_in[0];
    const float* W    = (const float*)d_in[1];
    const float* b    = (const float*)d_in[2];
    const float* U    = (const float*)d_in[3];
    const float* V    = (const float*)d_in[4];
    float* out = (float*)d_out;

    float* x = (float*)d_ws;                                   // 6.29 MB
    __hip_bfloat16* E = (__hip_bfloat16*)((char*)d_ws + (size_t)TOT_ROWS * D_HID * 4);
    // W hi/lo fragments live in the E region (E is written later by retrieve)
    __hip_bfloat16* Whi = E;
    __hip_bfloat16* Wlo = E + 36 * 8 * 64 * 8;                 // +147456 elems

    hipMemsetAsync(d_out, 0, sizeof(float), stream);

    prep_w_kernel<<<36 * 8, 64, 0, stream>>>(W, Whi, Wlo);
    xgemm_kernel<<<TOT_ROWS / 16, 256, 0, stream>>>(xall, Whi, Wlo, b, x);
    retrieve_kernel<<<TOT_ROWS / 4, 256, 0, stream>>>(x, U, V, E);

    // scale = ln2 (log2 -> ln) / (N rows * 60 pair-jobs)
    const float scale = 0.6931471805599453f / (2048.0f * 60.0f);
    pair_lse_kernel<<<480, 512, 0, stream>>>(E, out, scale);
}

// Round 6
// 163.617 us; speedup vs baseline: 4.2831x; 1.4788x over previous
//
#include <hip/hip_runtime.h>
#include <hip/hip_bf16.h>

// Problem constants
#define M_VIEWS 6
#define N_ROWS  2048
#define D_IN    1152
#define D_HID   128
#define D_K     64
#define TOT_ROWS (M_VIEWS * N_ROWS)   // 12288
// E is pre-scaled by sqrt((1/tau) * log2(e)) so E'.E' = (s/tau)*log2(e):
// pair-LSE softmax runs in exp2/log2 domain with no per-element muls.
#define SCALE_E 1.6986436f
#define LOG2E   1.4426950408889634f

typedef short bf16x8 __attribute__((ext_vector_type(8)));
typedef float f32x4  __attribute__((ext_vector_type(4)));

typedef __attribute__((address_space(1))) const void gvoid_t;
typedef __attribute__((address_space(3))) void svoid_t;

__device__ inline void async16(const void* g, void* l) {
    __builtin_amdgcn_global_load_lds((gvoid_t*)g, (svoid_t*)l, 16, 0, 0);
}

#if __has_builtin(__builtin_amdgcn_exp2f)
__device__ inline float fexp2(float x) { return __builtin_amdgcn_exp2f(x); }
#else
__device__ inline float fexp2(float x) { return exp2f(x); }
#endif
#if __has_builtin(__builtin_amdgcn_logf)
__device__ inline float flog2(float x) { return __builtin_amdgcn_logf(x); }
#else
__device__ inline float flog2(float x) { return log2f(x); }
#endif

// split f32 -> bf16 hi (x) + bf16 lo residual (y), returned by value
__device__ inline short2 splitf(float v) {
    __hip_bfloat16 hb = __float2bfloat16(v);
    float rem = v - __bfloat162float(hb);
    __hip_bfloat16 lb = __float2bfloat16(rem);
    short2 r;
    r.x = *reinterpret_cast<const short*>(&hb);
    r.y = *reinterpret_cast<const short*>(&lb);
    return r;
}

// ---------------------------------------------------------------------------
// Kernel 0a: split W into hi/lo bf16 in MFMA-fragment layout.
// ---------------------------------------------------------------------------
__global__ __launch_bounds__(64) void prep_w_kernel(
    const float* __restrict__ W,
    __hip_bfloat16* __restrict__ Whi, __hip_bfloat16* __restrict__ Wlo)
{
    const int s    = blockIdx.x >> 3;   // 0..35
    const int ct   = blockIdx.x & 7;    // 0..7
    const int lane = threadIdx.x;
    const int lg = lane >> 4, lr = lane & 15;
    bf16x8 hi, lo;
    #pragma unroll
    for (int i = 0; i < 8; ++i) {
        float w = W[(size_t)(s * 32 + lg * 8 + i) * D_HID + ct * 16 + lr];
        short2 hl = splitf(w);
        hi[i] = hl.x; lo[i] = hl.y;
    }
    size_t off = ((size_t)(s * 8 + ct) * 64 + lane) * 8;
    *reinterpret_cast<bf16x8*>(Whi + off) = hi;
    *reinterpret_cast<bf16x8*>(Wlo + off) = lo;
}

// ---------------------------------------------------------------------------
// Kernel 0b: U/V as MFMA B-fragments, hi/lo split.
// frags [0..15]: logits-B  B[k=d][c]   = P[d][c] * LOG2E   (f = s*4+ct)
// frags [16..31]: E-B      B[k=c][d]   = P[d][c]           (f = 16 + s2*8+ct2)
// ---------------------------------------------------------------------------
__global__ __launch_bounds__(64) void prep_p_kernel(
    const float* __restrict__ U, const float* __restrict__ V,
    __hip_bfloat16* __restrict__ Pfhi, __hip_bfloat16* __restrict__ Pflo)
{
    const int blk = blockIdx.x;       // 0..63
    const int mat = blk >> 5, f = blk & 31;
    const float* P = mat ? V : U;
    const int lane = threadIdx.x, lg = lane >> 4, lr = lane & 15;
    bf16x8 hi, lo;
    #pragma unroll
    for (int i = 0; i < 8; ++i) {
        float w;
        if (f < 16) {
            int s = f >> 2, ct = f & 3;
            w = P[(size_t)(s * 32 + lg * 8 + i) * D_K + ct * 16 + lr] * LOG2E;
        } else {
            int g = f - 16, s2 = g >> 3, ct2 = g & 7;
            w = P[(size_t)(ct2 * 16 + lr) * D_K + s2 * 32 + lg * 8 + i];
        }
        short2 hl = splitf(w);
        hi[i] = hl.x; lo[i] = hl.y;
    }
    size_t off = ((size_t)(mat * 32 + f) * 64 + lane) * 8;
    *reinterpret_cast<bf16x8*>(Pfhi + off) = hi;
    *reinterpret_cast<bf16x8*>(Pflo + off) = lo;
}

// ---------------------------------------------------------------------------
// Kernel 1: x = x_all @ W + b via split-bf16 MFMA, K-split over 4 waves.
// ---------------------------------------------------------------------------
__global__ __launch_bounds__(256) void xgemm_kernel(
    const float* __restrict__ xall,
    const __hip_bfloat16* __restrict__ Whi,
    const __hip_bfloat16* __restrict__ Wlo,
    const float* __restrict__ bias,
    float* __restrict__ x)
{
    __shared__ f32x4 red[3 * 512];   // 24 KB
    const int wave = threadIdx.x >> 6, lane = threadIdx.x & 63;
    const int lg = lane >> 4, lr = lane & 15;
    const int row0 = blockIdx.x * 16;
    const float* ap = xall + (size_t)(row0 + lr) * D_IN + wave * 288;

    f32x4 acc[8];
    #pragma unroll
    for (int ct = 0; ct < 8; ++ct) acc[ct] = {0.f, 0.f, 0.f, 0.f};

    const bf16x8* whb = reinterpret_cast<const bf16x8*>(Whi) + lane;
    const bf16x8* wlb = reinterpret_cast<const bf16x8*>(Wlo) + lane;

    for (int s = 0; s < 9; ++s) {
        const int gs = wave * 9 + s;
        const float* a8 = ap + s * 32 + lg * 8;
        float4 va = *reinterpret_cast<const float4*>(a8);
        float4 vb = *reinterpret_cast<const float4*>(a8 + 4);
        float v[8] = {va.x, va.y, va.z, va.w, vb.x, vb.y, vb.z, vb.w};
        bf16x8 ah, al;
        #pragma unroll
        for (int i = 0; i < 8; ++i) {
            short2 hl = splitf(v[i]);
            ah[i] = hl.x; al[i] = hl.y;
        }
        #pragma unroll
        for (int ct = 0; ct < 8; ++ct) {
            bf16x8 wh = whb[(size_t)(gs * 8 + ct) * 64];
            bf16x8 wl = wlb[(size_t)(gs * 8 + ct) * 64];
            acc[ct] = __builtin_amdgcn_mfma_f32_16x16x32_bf16(ah, wh, acc[ct], 0, 0, 0);
            acc[ct] = __builtin_amdgcn_mfma_f32_16x16x32_bf16(al, wh, acc[ct], 0, 0, 0);
            acc[ct] = __builtin_amdgcn_mfma_f32_16x16x32_bf16(ah, wl, acc[ct], 0, 0, 0);
        }
    }

    if (wave > 0) {
        #pragma unroll
        for (int ct = 0; ct < 8; ++ct)
            red[(wave - 1) * 512 + ct * 64 + lane] = acc[ct];
    }
    __syncthreads();
    if (wave == 0) {
        const int orow0 = row0 + lg * 4;
        #pragma unroll
        for (int ct = 0; ct < 8; ++ct) {
            f32x4 a = acc[ct];
            a += red[ct * 64 + lane];
            a += red[512 + ct * 64 + lane];
            a += red[1024 + ct * 64 + lane];
            float bj = bias[ct * 16 + lr];
            #pragma unroll
            for (int j = 0; j < 4; ++j)
                x[(size_t)(orow0 + j) * D_HID + ct * 16 + lr] = a[j] + bj;
        }
    }
}

// ---------------------------------------------------------------------------
// Kernel 2: retrieve via MFMA. One wave = 16 rows.
// logits = x @ (P*log2e)  [K=128] -> softmax (exp2 domain, reduce over 16
// lr-lanes) -> attn (LDS bounce, pad-72) -> E = attn @ P^T [K=64] -> bf16.
// All GEMMs split-bf16 (hi*hi + lo*hi + hi*lo).
// ---------------------------------------------------------------------------
__global__ __launch_bounds__(64) void retrieve_kernel(
    const float* __restrict__ x,
    const __hip_bfloat16* __restrict__ Pfhi,
    const __hip_bfloat16* __restrict__ Pflo,
    __hip_bfloat16* __restrict__ E)
{
    __shared__ float al[16 * 72];   // attn, row stride 72 (16B-aligned rows)
    const int lane = threadIdx.x;
    const int lg = lane >> 4, lr = lane & 15;
    const int row0 = blockIdx.x * 16;

    // x A-fragments, split hi/lo
    bf16x8 xh[4], xl[4];
    const float* xp = x + (size_t)(row0 + lr) * D_HID;
    #pragma unroll
    for (int s = 0; s < 4; ++s) {
        float4 va = *reinterpret_cast<const float4*>(xp + s * 32 + lg * 8);
        float4 vb = *reinterpret_cast<const float4*>(xp + s * 32 + lg * 8 + 4);
        float v[8] = {va.x, va.y, va.z, va.w, vb.x, vb.y, vb.z, vb.w};
        #pragma unroll
        for (int i = 0; i < 8; ++i) {
            short2 hl = splitf(v[i]);
            xh[s][i] = hl.x; xl[s][i] = hl.y;
        }
    }

    #pragma unroll
    for (int mat = 0; mat < 2; ++mat) {
        const bf16x8* bh = reinterpret_cast<const bf16x8*>(Pfhi) + (size_t)mat * 32 * 64 + lane;
        const bf16x8* bl = reinterpret_cast<const bf16x8*>(Pflo) + (size_t)mat * 32 * 64 + lane;

        // logits GEMM: 16 rows x 64 cols, K=128
        f32x4 lacc[4];
        #pragma unroll
        for (int ct = 0; ct < 4; ++ct) lacc[ct] = {0.f, 0.f, 0.f, 0.f};
        #pragma unroll
        for (int ct = 0; ct < 4; ++ct) {
            #pragma unroll
            for (int s = 0; s < 4; ++s) {
                bf16x8 wh = bh[(s * 4 + ct) * 64];
                bf16x8 wl = bl[(s * 4 + ct) * 64];
                lacc[ct] = __builtin_amdgcn_mfma_f32_16x16x32_bf16(xh[s], wh, lacc[ct], 0, 0, 0);
                lacc[ct] = __builtin_amdgcn_mfma_f32_16x16x32_bf16(xl[s], wh, lacc[ct], 0, 0, 0);
                lacc[ct] = __builtin_amdgcn_mfma_f32_16x16x32_bf16(xh[s], wl, lacc[ct], 0, 0, 0);
            }
        }

        // softmax per row (row = lg*4+j; its 64 cols live on the 16 lr-lanes)
        #pragma unroll
        for (int j = 0; j < 4; ++j) {
            float l0 = lacc[0][j], l1 = lacc[1][j], l2 = lacc[2][j], l3 = lacc[3][j];
            float mx = fmaxf(fmaxf(l0, l1), fmaxf(l2, l3));
            #pragma unroll
            for (int s = 1; s < 16; s <<= 1) mx = fmaxf(mx, __shfl_xor(mx, s));
            float p0 = fexp2(l0 - mx), p1 = fexp2(l1 - mx);
            float p2 = fexp2(l2 - mx), p3 = fexp2(l3 - mx);
            float sm = p0 + p1 + p2 + p3;
            #pragma unroll
            for (int s = 1; s < 16; s <<= 1) sm += __shfl_xor(sm, s);
            float inv = 1.0f / sm;
            float* ar = al + (lg * 4 + j) * 72;
            ar[lr]      = p0 * inv;
            ar[16 + lr] = p1 * inv;
            ar[32 + lr] = p2 * inv;
            ar[48 + lr] = p3 * inv;
        }
        __syncthreads();   // LDS RAW across lanes

        // attn A-fragments (row = lr), split hi/lo
        bf16x8 aah[2], aal[2];
        #pragma unroll
        for (int s2 = 0; s2 < 2; ++s2) {
            const float* ap = al + lr * 72 + s2 * 32 + lg * 8;
            float4 va = *reinterpret_cast<const float4*>(ap);
            float4 vb = *reinterpret_cast<const float4*>(ap + 4);
            float v[8] = {va.x, va.y, va.z, va.w, vb.x, vb.y, vb.z, vb.w};
            #pragma unroll
            for (int i = 0; i < 8; ++i) {
                short2 hl = splitf(v[i]);
                aah[s2][i] = hl.x; aal[s2][i] = hl.y;
            }
        }

        // E GEMM: 16 rows x 128 cols, K=64
        f32x4 eacc[8];
        #pragma unroll
        for (int ct2 = 0; ct2 < 8; ++ct2) eacc[ct2] = {0.f, 0.f, 0.f, 0.f};
        #pragma unroll
        for (int ct2 = 0; ct2 < 8; ++ct2) {
            #pragma unroll
            for (int s2 = 0; s2 < 2; ++s2) {
                bf16x8 wh = bh[(16 + s2 * 8 + ct2) * 64];
                bf16x8 wl = bl[(16 + s2 * 8 + ct2) * 64];
                eacc[ct2] = __builtin_amdgcn_mfma_f32_16x16x32_bf16(aah[s2], wh, eacc[ct2], 0, 0, 0);
                eacc[ct2] = __builtin_amdgcn_mfma_f32_16x16x32_bf16(aal[s2], wh, eacc[ct2], 0, 0, 0);
                eacc[ct2] = __builtin_amdgcn_mfma_f32_16x16x32_bf16(aah[s2], wl, eacc[ct2], 0, 0, 0);
            }
        }

        __hip_bfloat16* Er = E + ((size_t)mat * TOT_ROWS + row0) * D_HID;
        #pragma unroll
        for (int ct2 = 0; ct2 < 8; ++ct2) {
            #pragma unroll
            for (int j = 0; j < 4; ++j)
                Er[(size_t)(lg * 4 + j) * D_HID + ct2 * 16 + lr] =
                    __float2bfloat16(eacc[ct2][j] * SCALE_E);
        }
        __syncthreads();   // WAR: next mat rewrites al
    }
}

// ---------------------------------------------------------------------------
// Kernel 3: pair LSE. Block = (job, q-tile of 256 rows), 8 waves x 32 rows.
// Fragment-ordered LDS staging (conflict-free), double-buffered,
// per-lane online LSE in exp2 domain, XCD-swizzled blockIdx.
// ---------------------------------------------------------------------------
__global__ __launch_bounds__(512) void pair_lse_kernel(
    const __hip_bfloat16* __restrict__ E,  // [2][6][2048][128], pre-scaled
    float* __restrict__ out, float scale)
{
    __shared__ __align__(16) unsigned char kbuf[2 * 16384];
    __shared__ float bsum[8];

    const int bid    = blockIdx.x;
    const int linear = (bid & 7) * 60 + (bid >> 3);
    const int qt  = linear & 7;          // 0..7
    const int job = linear >> 3;         // 0..59
    const int mat = job / 30;
    const int pr  = job % 30;
    const int m   = pr / 5;
    int k = pr % 5; k += (k >= m);

    const __hip_bfloat16* Qm = E + ((size_t)(mat * M_VIEWS + m)) * N_ROWS * D_HID;
    const __hip_bfloat16* Kk = E + ((size_t)(mat * M_VIEWS + k)) * N_ROWS * D_HID;

    const int tid  = threadIdx.x;
    const int wave = tid >> 6, lane = tid & 63;
    const int lr = lane & 15, lg = lane >> 4;

    const int qrow0 = qt * 256 + wave * 32;

    bf16x8 afrag[2][4];
    #pragma unroll
    for (int rf = 0; rf < 2; ++rf) {
        const __hip_bfloat16* qp = Qm + (size_t)(qrow0 + rf * 16 + lr) * D_HID;
        #pragma unroll
        for (int s = 0; s < 4; ++s)
            afrag[rf][s] = *reinterpret_cast<const bf16x8*>(qp + s * 32 + lg * 8);
    }

    float mrun[2][4], lrun[2][4], pos[2][4];
    #pragma unroll
    for (int rf = 0; rf < 2; ++rf)
        #pragma unroll
        for (int j = 0; j < 4; ++j) {
            mrun[rf][j] = -1e30f; lrun[rf][j] = 0.f; pos[rf][j] = 0.f;
        }

    const int ptdiag = qt * 4 + (wave >> 1);
    const int ctd0   = (wave & 1) * 2;

    #define STAGE(pt, b)                                                        \
        {                                                                       \
            const char* base = (const char*)Kk + (size_t)(pt) * 16384;          \
            _Pragma("unroll")                                                   \
            for (int i = 0; i < 2; ++i) {                                       \
                int f = wave * 2 + i;                                           \
                int ct_ = f >> 2, s_ = f & 3;                                   \
                async16(base + (ct_ * 16 + lr) * 256 + s_ * 64 + lg * 16,       \
                        kbuf + (b) * 16384 + f * 1024);                         \
            }                                                                   \
        }

    STAGE(0, 0);
    __syncthreads();

    const unsigned char* kb0 = kbuf + lane * 16;
    int buf = 0;
    for (int pt = 0; pt < 32; ++pt) {
        if (pt < 31) STAGE(pt + 1, buf ^ 1);

        const unsigned char* kb = kb0 + buf * 16384;
        f32x4 acc[2][4];
        #pragma unroll
        for (int rf = 0; rf < 2; ++rf)
            #pragma unroll
            for (int ct = 0; ct < 4; ++ct) acc[rf][ct] = {0.f, 0.f, 0.f, 0.f};

        #pragma unroll
        for (int ct = 0; ct < 4; ++ct) {
            #pragma unroll
            for (int s = 0; s < 4; ++s) {
                bf16x8 bf = *reinterpret_cast<const bf16x8*>(kb + (ct * 4 + s) * 1024);
                acc[0][ct] = __builtin_amdgcn_mfma_f32_16x16x32_bf16(afrag[0][s], bf, acc[0][ct], 0, 0, 0);
                acc[1][ct] = __builtin_amdgcn_mfma_f32_16x16x32_bf16(afrag[1][s], bf, acc[1][ct], 0, 0, 0);
            }
        }

        const bool dtile = (pt == ptdiag);
        #pragma unroll
        for (int rf = 0; rf < 2; ++rf) {
            #pragma unroll
            for (int j = 0; j < 4; ++j) {
                float v0 = acc[rf][0][j], v1 = acc[rf][1][j];
                float v2 = acc[rf][2][j], v3 = acc[rf][3][j];
                if (dtile) {
                    const int cd = ctd0 + rf;     // wave-uniform
                    const bool dl = (lr == lg * 4 + j);
                    float dv = (cd == 0) ? v0 : (cd == 1) ? v1 : (cd == 2) ? v2 : v3;
                    if (dl) {
                        pos[rf][j] = dv;
                        if      (cd == 0) v0 = -INFINITY;
                        else if (cd == 1) v1 = -INFINITY;
                        else if (cd == 2) v2 = -INFINITY;
                        else              v3 = -INFINITY;
                    }
                }
                float tmax = fmaxf(fmaxf(v0, v1), fmaxf(v2, v3));
                float nm = fmaxf(mrun[rf][j], tmax);
                float ps = fexp2(v0 - nm) + fexp2(v1 - nm)
                         + fexp2(v2 - nm) + fexp2(v3 - nm);
                lrun[rf][j] = lrun[rf][j] * fexp2(mrun[rf][j] - nm) + ps;
                mrun[rf][j] = nm;
            }
        }
        __syncthreads();
        buf ^= 1;
    }

    float contrib = 0.f;
    #pragma unroll
    for (int rf = 0; rf < 2; ++rf) {
        #pragma unroll
        for (int j = 0; j < 4; ++j) {
            float Mv = mrun[rf][j], Lv = lrun[rf][j];
            #pragma unroll
            for (int s = 1; s < 16; s <<= 1) {
                float Mo = __shfl_xor(Mv, s);
                float Lo = __shfl_xor(Lv, s);
                float nm = fmaxf(Mv, Mo);
                Lv = Lv * fexp2(Mv - nm) + Lo * fexp2(Mo - nm);
                Mv = nm;
            }
            float P = pos[rf][j];
            #pragma unroll
            for (int s = 1; s < 16; s <<= 1) P += __shfl_xor(P, s);
            if (lr == 0) contrib += (Mv + flog2(Lv)) - P;
        }
    }
    #pragma unroll
    for (int s = 1; s < 64; s <<= 1) contrib += __shfl_xor(contrib, s);

    if (lane == 0) bsum[wave] = contrib;
    __syncthreads();
    if (tid == 0) {
        float t = 0.f;
        #pragma unroll
        for (int w = 0; w < 8; ++w) t += bsum[w];
        atomicAdd(out, t * scale);
    }
}

// ---------------------------------------------------------------------------
extern "C" void kernel_launch(void* const* d_in, const int* in_sizes, int n_in,
                              void* d_out, int out_size, void* d_ws, size_t ws_size,
                              hipStream_t stream) {
    const float* xall = (const float*)d_in[0];
    const float* W    = (const float*)d_in[1];
    const float* b    = (const float*)d_in[2];
    const float* U    = (const float*)d_in[3];
    const float* V    = (const float*)d_in[4];
    float* out = (float*)d_out;

    float* x = (float*)d_ws;                                   // 6.29 MB
    __hip_bfloat16* E = (__hip_bfloat16*)((char*)d_ws + (size_t)TOT_ROWS * D_HID * 4);
    // W hi/lo fragments overlay E (consumed by xgemm before retrieve writes E)
    __hip_bfloat16* Whi = E;
    __hip_bfloat16* Wlo = E + 36 * 8 * 64 * 8;                 // +147456 elems
    // P fragments after E region: 2 x 64 KB
    __hip_bfloat16* Pfhi = (__hip_bfloat16*)((char*)d_ws + 2 * (size_t)TOT_ROWS * D_HID * 4);
    __hip_bfloat16* Pflo = Pfhi + 2 * 32 * 64 * 8;             // +32768 elems

    (void)hipMemsetAsync(d_out, 0, sizeof(float), stream);

    prep_w_kernel<<<36 * 8, 64, 0, stream>>>(W, Whi, Wlo);
    prep_p_kernel<<<64, 64, 0, stream>>>(U, V, Pfhi, Pflo);
    xgemm_kernel<<<TOT_ROWS / 16, 256, 0, stream>>>(xall, Whi, Wlo, b, x);
    retrieve_kernel<<<TOT_ROWS / 16, 64, 0, stream>>>(x, Pfhi, Pflo, E);

    // scale = ln2 (log2 -> ln) / (N rows * 60 pair-jobs)
    const float scale = 0.6931471805599453f / (2048.0f * 60.0f);
    pair_lse_kernel<<<480, 512, 0, stream>>>(E, out, scale);
}